// Round 9
// baseline (182.882 us; speedup 1.0000x reference)
//
#include <hip/hip_runtime.h>

#define N_NODES 50000
#define N_EDGES 600000
#define D 128
#define BN_EPS 1e-5f
#define NBLK_SCAN 196   // ceil(50000/256)

// ws layout in 4-byte words:
#define OFF_CNT_OUT   0            // int[50048]
#define OFF_CNT_IN    50048        // int[50048]
#define OFF_SUMS8     100096       // float[8*128]
#define OFF_SUMSQ8    101120       // float[8*128]
#define ZERO_WORDS    102144       // memset range each call
#define OFF_PART      102144       // int[256] (fully overwritten)
#define OFF_ND        102400       // float[50048]
#define OFF_ROWSTART  152448       // int[50052]
#define OFF_CURSOR    202500       // int[50048]
#define OFF_CSR       252548       // int[600000]
#define OFF_WPK       852548       // bf16[128*128] packed B-frags (16B aligned)
#define OFF_WRPK      860740       // bf16[128*128]
#define OFF_XS        868932       // bf16[50000*128] = X * norm_src (16B aligned)
// total = 4,068,932 words = 16.28 MB (< 16.47 MB proven in R4/R6)

typedef __attribute__((ext_vector_type(8))) __bf16 bf16x8;
typedef __attribute__((ext_vector_type(4))) float f32x4;

static __device__ __forceinline__ unsigned short f2bf(float f) {
    unsigned u = __float_as_uint(f);
    unsigned r = (u + 0x7FFFu + ((u >> 16) & 1u)) >> 16;
    return (unsigned short)r;
}
static __device__ __forceinline__ float bf2f(unsigned short h) {
    return __uint_as_float(((unsigned)h) << 16);
}

// ---------------- degrees (int2-vectorized) + fused W packing ----------------
// packW: frag (c=coltile 0..7, t=ktile 0..3): lane l holds B[t*32+(l>>4)*8+j][c*16+(l&15)]
__global__ void deg_pack_kernel(const int* __restrict__ src, const int* __restrict__ dst,
                                int* __restrict__ cnt_out, int* __restrict__ cnt_in,
                                const float* __restrict__ W, const float* __restrict__ Wres,
                                unsigned short* __restrict__ Wpk, unsigned short* __restrict__ Wrpk) {
    int i = blockIdx.x * 256 + threadIdx.x;
    if (i < 2048) {
        int l = i & 63;
        int t = (i >> 6) & 3;
        int c = i >> 8;
        int col = c * 16 + (l & 15);
        int k0 = t * 32 + (l >> 4) * 8;
        union { unsigned short us[8]; uint4 v; } u1, u2;
        #pragma unroll
        for (int j = 0; j < 8; ++j) {
            u1.us[j] = f2bf(W[(size_t)(k0 + j) * 128 + col]);
            u2.us[j] = f2bf(Wres[(size_t)(k0 + j) * 128 + col]);
        }
        ((uint4*)Wpk)[i] = u1.v;
        ((uint4*)Wrpk)[i] = u2.v;
    }
    if (i < N_EDGES / 2) {
        int2 s2 = ((const int2*)src)[i];
        int2 d2 = ((const int2*)dst)[i];
        atomicAdd(&cnt_out[s2.x], 1);
        atomicAdd(&cnt_out[s2.y], 1);
        atomicAdd(&cnt_in[d2.x], 1);
        atomicAdd(&cnt_in[d2.y], 1);
    }
}

// ---------------- X * rsqrt(deg_out) -> bf16 Xs (one thread per 8 elems, 3125 blocks) ----------------
__global__ void cvt_kernel(const float* __restrict__ X, const int* __restrict__ cnt_out,
                           unsigned short* __restrict__ Xs) {
    int tid = blockIdx.x * 256 + threadIdx.x;
    if (tid >= N_NODES * 16) return;
    int row = tid >> 4;
    int sub = tid & 15;
    float wv = rsqrtf((float)max(cnt_out[row], 1));
    const float4* xp = (const float4*)(X + (size_t)row * 128 + sub * 8);
    float4 a = xp[0];
    float4 b = xp[1];
    union { unsigned short us[8]; uint4 u; } o;
    o.us[0] = f2bf(a.x * wv); o.us[1] = f2bf(a.y * wv);
    o.us[2] = f2bf(a.z * wv); o.us[3] = f2bf(a.w * wv);
    o.us[4] = f2bf(b.x * wv); o.us[5] = f2bf(b.y * wv);
    o.us[6] = f2bf(b.z * wv); o.us[7] = f2bf(b.w * wv);
    *(uint4*)(Xs + (size_t)row * 128 + sub * 8) = o.u;
}

// ---------------- scan level A: block sums of cnt_in ----------------
__global__ void scanA_kernel(const int* __restrict__ cnt_in, int* __restrict__ part) {
    __shared__ int wsum[4];
    int i = blockIdx.x * 256 + threadIdx.x;
    int v = (i < N_NODES) ? cnt_in[i] : 0;
    int lane = threadIdx.x & 63;
    int wid = threadIdx.x >> 6;
    int s = v;
    #pragma unroll
    for (int off = 32; off >= 1; off >>= 1) s += __shfl_xor(s, off);
    if (lane == 0) wsum[wid] = s;
    __syncthreads();
    if (threadIdx.x == 0) part[blockIdx.x] = wsum[0] + wsum[1] + wsum[2] + wsum[3];
}

// ---------------- scan C (fused B): prefix base via masked reduce + local scan; writes nd too ----------------
__global__ void scanC_kernel(const int* __restrict__ cnt_in, const int* __restrict__ part,
                             int* __restrict__ row_start, int* __restrict__ cursor,
                             float* __restrict__ nd) {
    __shared__ int wsumB[4];
    __shared__ int wsum[4];
    int t = threadIdx.x;
    int lane = t & 63;
    int wid = t >> 6;
    // masked reduce of part[0..blockIdx.x-1]
    int pv = (t < NBLK_SCAN && t < (int)blockIdx.x) ? part[t] : 0;
    int sb = pv;
    #pragma unroll
    for (int off = 32; off >= 1; off >>= 1) sb += __shfl_xor(sb, off);
    if (lane == 0) wsumB[wid] = sb;
    // local exclusive scan of this block's cnt chunk
    int i = blockIdx.x * 256 + t;
    int v = (i < N_NODES) ? cnt_in[i] : 0;
    if (i < N_NODES) nd[i] = rsqrtf((float)max(v, 1));
    int s = v;
    #pragma unroll
    for (int off = 1; off < 64; off <<= 1) {
        int u = __shfl_up(s, off);
        if (lane >= off) s += u;
    }
    if (lane == 63) wsum[wid] = s;
    __syncthreads();
    int add = wsumB[0] + wsumB[1] + wsumB[2] + wsumB[3];
    for (int k = 0; k < wid; ++k) add += wsum[k];
    if (i < N_NODES) {
        int rs = add + s - v;
        row_start[i] = rs;
        cursor[i] = rs;
    }
    if (i == N_NODES) row_start[N_NODES] = N_EDGES;
}

// ---------------- CSR fill (int2-vectorized) ----------------
__global__ void fill_kernel(const int* __restrict__ src, const int* __restrict__ dst,
                            int* __restrict__ cursor, int* __restrict__ csr) {
    int i = blockIdx.x * blockDim.x + threadIdx.x;
    if (i < N_EDGES / 2) {
        int2 d2 = ((const int2*)dst)[i];
        int2 s2 = ((const int2*)src)[i];
        int p0 = atomicAdd(&cursor[d2.x], 1);
        csr[p0] = s2.x;
        int p1 = atomicAdd(&cursor[d2.y], 1);
        csr[p1] = s2.y;
    }
}

// ---------------- fused gather + dual MFMA GEMM + relu/residual + BN partials ----------------
// 256 threads = 4 waves, block = one 16-row tile (grid 3125).
// Gather: wave w owns rows w*4..w*4+3, ROW-INTERLEAVED: per iteration, one 4-edge wide
// load per live row (16-lane group per edge, 16B per lane) -> 4 independent csr->Xs chains.
// Combine via shfl_xor(16/32) once per row at the end. MFMA: wave w does coltiles 2w, 2w+1.
__global__ __launch_bounds__(256) void fused_kernel(
    const float* __restrict__ X, const unsigned short* __restrict__ Xs,
    const int* __restrict__ csr, const int* __restrict__ row_start,
    const float* __restrict__ nd,
    const unsigned short* __restrict__ Wpk, const unsigned short* __restrict__ Wrpk,
    float* __restrict__ out, float* __restrict__ sums8, float* __restrict__ sumsq8) {
    __shared__ unsigned short P[16 * 136];  // 4.25KB, 272B row stride
    __shared__ float lsum[128];
    __shared__ float lsq[128];
    int t = threadIdx.x;
    int w = t >> 6;
    int l = t & 63;
    int sub = l & 15;   // col slice: cols sub*8 .. sub*8+7
    int grp = l >> 4;   // edge slot within a 4-edge step
    int rt = blockIdx.x;

    // ---- row ranges: one vector load + shfl broadcast ----
    int node0 = rt * 16 + w * 4;
    int rs5[5];
    {
        int vv = row_start[node0 + (l < 5 ? l : 4)];
        #pragma unroll
        for (int k = 0; k < 5; ++k) rs5[k] = __shfl(vv, k);
    }

    // ---- interleaved gather: 4 independent chains ----
    float acc[4][8];
    #pragma unroll
    for (int r = 0; r < 4; ++r)
        #pragma unroll
        for (int j = 0; j < 8; ++j) acc[r][j] = 0.f;
    int cur0 = rs5[0], cur1 = rs5[1], cur2 = rs5[2], cur3 = rs5[3];
    int end0 = rs5[1], end1 = rs5[2], end2 = rs5[3], end3 = rs5[4];
    while ((cur0 < end0) | (cur1 < end1) | (cur2 < end2) | (cur3 < end3)) {
        if (cur0 < end0) {
            int idx = cur0 + grp;
            if (idx < end0) {
                int s = csr[idx];
                uint4 v = *(const uint4*)(Xs + (size_t)s * 128 + sub * 8);
                acc[0][0] += __uint_as_float(v.x << 16);
                acc[0][1] += __uint_as_float(v.x & 0xFFFF0000u);
                acc[0][2] += __uint_as_float(v.y << 16);
                acc[0][3] += __uint_as_float(v.y & 0xFFFF0000u);
                acc[0][4] += __uint_as_float(v.z << 16);
                acc[0][5] += __uint_as_float(v.z & 0xFFFF0000u);
                acc[0][6] += __uint_as_float(v.w << 16);
                acc[0][7] += __uint_as_float(v.w & 0xFFFF0000u);
            }
            cur0 += 4;
        }
        if (cur1 < end1) {
            int idx = cur1 + grp;
            if (idx < end1) {
                int s = csr[idx];
                uint4 v = *(const uint4*)(Xs + (size_t)s * 128 + sub * 8);
                acc[1][0] += __uint_as_float(v.x << 16);
                acc[1][1] += __uint_as_float(v.x & 0xFFFF0000u);
                acc[1][2] += __uint_as_float(v.y << 16);
                acc[1][3] += __uint_as_float(v.y & 0xFFFF0000u);
                acc[1][4] += __uint_as_float(v.z << 16);
                acc[1][5] += __uint_as_float(v.z & 0xFFFF0000u);
                acc[1][6] += __uint_as_float(v.w << 16);
                acc[1][7] += __uint_as_float(v.w & 0xFFFF0000u);
            }
            cur1 += 4;
        }
        if (cur2 < end2) {
            int idx = cur2 + grp;
            if (idx < end2) {
                int s = csr[idx];
                uint4 v = *(const uint4*)(Xs + (size_t)s * 128 + sub * 8);
                acc[2][0] += __uint_as_float(v.x << 16);
                acc[2][1] += __uint_as_float(v.x & 0xFFFF0000u);
                acc[2][2] += __uint_as_float(v.y << 16);
                acc[2][3] += __uint_as_float(v.y & 0xFFFF0000u);
                acc[2][4] += __uint_as_float(v.z << 16);
                acc[2][5] += __uint_as_float(v.z & 0xFFFF0000u);
                acc[2][6] += __uint_as_float(v.w << 16);
                acc[2][7] += __uint_as_float(v.w & 0xFFFF0000u);
            }
            cur2 += 4;
        }
        if (cur3 < end3) {
            int idx = cur3 + grp;
            if (idx < end3) {
                int s = csr[idx];
                uint4 v = *(const uint4*)(Xs + (size_t)s * 128 + sub * 8);
                acc[3][0] += __uint_as_float(v.x << 16);
                acc[3][1] += __uint_as_float(v.x & 0xFFFF0000u);
                acc[3][2] += __uint_as_float(v.y << 16);
                acc[3][3] += __uint_as_float(v.y & 0xFFFF0000u);
                acc[3][4] += __uint_as_float(v.z << 16);
                acc[3][5] += __uint_as_float(v.z & 0xFFFF0000u);
                acc[3][6] += __uint_as_float(v.w << 16);
                acc[3][7] += __uint_as_float(v.w & 0xFFFF0000u);
            }
            cur3 += 4;
        }
    }
    // combine groups + write row sums to LDS
    #pragma unroll
    for (int r = 0; r < 4; ++r) {
        #pragma unroll
        for (int j = 0; j < 8; ++j) {
            acc[r][j] += __shfl_xor(acc[r][j], 16);
            acc[r][j] += __shfl_xor(acc[r][j], 32);
        }
        if (l < 16) {
            union { unsigned short us[8]; uint4 u; } o;
            #pragma unroll
            for (int j = 0; j < 8; ++j) o.us[j] = f2bf(acc[r][j]);
            *(uint4*)(&P[(w * 4 + r) * 136 + sub * 8]) = o.u;
        }
    }
    __syncthreads();

    // ---- fragment loads: A1 from P (* nd), A2 from f32 X ----
    int kg = l >> 4;
    int lr = l & 15;
    int arow = rt * 16 + lr;           // always < 50000
    float ndv = nd[arow];
    bf16x8 a1[4], a2[4];
    #pragma unroll
    for (int kt = 0; kt < 4; ++kt) {
        union { unsigned short us[8]; uint4 v; bf16x8 b; } v0, o1, o2;
        v0.v = *(const uint4*)(&P[lr * 136 + kt * 32 + kg * 8]);
        #pragma unroll
        for (int j = 0; j < 8; ++j) o1.us[j] = f2bf(bf2f(v0.us[j]) * ndv);
        a1[kt] = o1.b;
        float4 xa = *(const float4*)(X + (size_t)arow * 128 + kt * 32 + kg * 8);
        float4 xb = *(const float4*)(X + (size_t)arow * 128 + kt * 32 + kg * 8 + 4);
        o2.us[0] = f2bf(xa.x); o2.us[1] = f2bf(xa.y); o2.us[2] = f2bf(xa.z); o2.us[3] = f2bf(xa.w);
        o2.us[4] = f2bf(xb.x); o2.us[5] = f2bf(xb.y); o2.us[6] = f2bf(xb.z); o2.us[7] = f2bf(xb.w);
        a2[kt] = o2.b;
    }
    const bf16x8* BW = (const bf16x8*)Wpk;
    const bf16x8* BR = (const bf16x8*)Wrpk;

    // ---- MFMA + epilogue: wave w handles coltiles 2w, 2w+1 (col partition -> plain stores) ----
    #pragma unroll
    for (int ci = 0; ci < 2; ++ci) {
        int c = w * 2 + ci;
        f32x4 acc1 = {0.f, 0.f, 0.f, 0.f};
        f32x4 acc2 = {0.f, 0.f, 0.f, 0.f};
        #pragma unroll
        for (int kt = 0; kt < 4; ++kt)
            acc1 = __builtin_amdgcn_mfma_f32_16x16x32_bf16(a1[kt], BW[(c * 4 + kt) * 64 + l], acc1, 0, 0, 0);
        #pragma unroll
        for (int kt = 0; kt < 4; ++kt)
            acc2 = __builtin_amdgcn_mfma_f32_16x16x32_bf16(a2[kt], BR[(c * 4 + kt) * 64 + l], acc2, 0, 0, 0);
        int col = c * 16 + lr;
        float s = 0.f, s2 = 0.f;
        #pragma unroll
        for (int i = 0; i < 4; ++i) {
            int crow = rt * 16 + kg * 4 + i;  // C/D: col=lane&15, row=(lane>>4)*4+i
            float v = fmaxf(acc1[i], 0.f) + fmaxf(acc2[i], 0.f);
            out[(size_t)crow * 128 + col] = v;
            s += v;
            s2 += v * v;
        }
        s += __shfl_xor(s, 16);
        s2 += __shfl_xor(s2, 16);
        s += __shfl_xor(s, 32);
        s2 += __shfl_xor(s2, 32);
        if (l < 16) {
            lsum[col] = s;   // each col written by exactly one wave/lane
            lsq[col] = s2;
        }
    }
    __syncthreads();
    if (t < 128) {
        int slot = (blockIdx.x & 7) * 128 + t;
        atomicAdd(&sums8[slot], lsum[t]);
        atomicAdd(&sumsq8[slot], lsq[t]);
    }
}

// ---------------- BatchNorm apply (8-slot reduce in LDS, in-place float4) ----------------
__global__ void bn_apply_kernel(float* __restrict__ out, const float* __restrict__ sums8,
                                const float* __restrict__ sumsq8, const float* __restrict__ gamma,
                                const float* __restrict__ beta) {
    __shared__ float lmean[128], linv[128], lg[128], lb[128];
    int t = threadIdx.x;
    if (t < 128) {
        float s = 0.f, s2 = 0.f;
        #pragma unroll
        for (int k = 0; k < 8; ++k) {
            s += sums8[k * 128 + t];
            s2 += sumsq8[k * 128 + t];
        }
        const float invN = 1.0f / (float)N_NODES;
        float m = s * invN;
        lmean[t] = m;
        linv[t] = rsqrtf(s2 * invN - m * m + BN_EPS);
        lg[t] = gamma[t];
        lb[t] = beta[t];
    }
    __syncthreads();
    int tid = blockIdx.x * 256 + t;
    if (tid >= N_NODES * D / 4) return;
    int d0 = (tid * 4) & 127;
    float4 v = ((float4*)out)[tid];
    v.x = lg[d0] * (v.x - lmean[d0]) * linv[d0] + lb[d0];
    v.y = lg[d0 + 1] * (v.y - lmean[d0 + 1]) * linv[d0 + 1] + lb[d0 + 1];
    v.z = lg[d0 + 2] * (v.z - lmean[d0 + 2]) * linv[d0 + 2] + lb[d0 + 2];
    v.w = lg[d0 + 3] * (v.w - lmean[d0 + 3]) * linv[d0 + 3] + lb[d0 + 3];
    ((float4*)out)[tid] = v;
}

extern "C" void kernel_launch(void* const* d_in, const int* in_sizes, int n_in,
                              void* d_out, int out_size, void* d_ws, size_t ws_size,
                              hipStream_t stream) {
    const float* X = (const float*)d_in[0];
    const float* W = (const float*)d_in[1];
    const float* Wres = (const float*)d_in[2];
    const float* gamma = (const float*)d_in[3];
    const float* beta = (const float*)d_in[4];
    const int* src = (const int*)d_in[5];
    const int* dst = (const int*)d_in[6];
    float* out = (float*)d_out;

    int* wsI = (int*)d_ws;
    int* cnt_out = wsI + OFF_CNT_OUT;
    int* cnt_in = wsI + OFF_CNT_IN;
    float* sums8 = (float*)(wsI + OFF_SUMS8);
    float* sumsq8 = (float*)(wsI + OFF_SUMSQ8);
    int* part = wsI + OFF_PART;
    float* nd = (float*)(wsI + OFF_ND);
    int* row_start = wsI + OFF_ROWSTART;
    int* cursor = wsI + OFF_CURSOR;
    int* csr = wsI + OFF_CSR;
    unsigned short* Wpk = (unsigned short*)(wsI + OFF_WPK);
    unsigned short* Wrpk = (unsigned short*)(wsI + OFF_WRPK);
    unsigned short* Xs = (unsigned short*)(wsI + OFF_XS);

    hipMemsetAsync(d_ws, 0, (size_t)ZERO_WORDS * 4, stream);

    deg_pack_kernel<<<(N_EDGES / 2 + 255) / 256, 256, 0, stream>>>(src, dst, cnt_out, cnt_in,
                                                                   W, Wres, Wpk, Wrpk);
    cvt_kernel<<<(N_NODES * 16 + 255) / 256, 256, 0, stream>>>(X, cnt_out, Xs);
    scanA_kernel<<<NBLK_SCAN, 256, 0, stream>>>(cnt_in, part);
    scanC_kernel<<<NBLK_SCAN, 256, 0, stream>>>(cnt_in, part, row_start, cursor, nd);
    fill_kernel<<<(N_EDGES / 2 + 255) / 256, 256, 0, stream>>>(src, dst, cursor, csr);
    fused_kernel<<<N_NODES / 16, 256, 0, stream>>>(X, Xs, csr, row_start, nd,
                                                   Wpk, Wrpk, out, sums8, sumsq8);
    bn_apply_kernel<<<(N_NODES * D / 4 + 255) / 256, 256, 0, stream>>>(out, sums8, sumsq8,
                                                                       gamma, beta);
}

// Round 10
// 174.428 us; speedup vs baseline: 1.0485x; 1.0485x over previous
//
#include <hip/hip_runtime.h>

#define N_NODES 50000
#define N_EDGES 600000
#define D 128
#define BN_EPS 1e-5f
#define NBLK_SCAN 196   // ceil(50000/256)

// ws layout in 4-byte words:
#define OFF_CNT_OUT   0            // int[50048]
#define OFF_CNT_IN    50048        // int[50048]
#define OFF_SUMS8     100096       // float[8*128]
#define OFF_SUMSQ8    101120       // float[8*128]
#define ZERO_WORDS    102144       // memset range each call
#define OFF_PART      102144       // int[256] (fully overwritten)
#define OFF_ND        102400       // float[50048]
#define OFF_ROWSTART  152448       // int[50052]
#define OFF_CURSOR    202500       // int[50048]
#define OFF_CSR       252548       // int[600000]
#define OFF_WPK       852548       // bf16[128*128] packed B-frags (16B aligned)
#define OFF_WRPK      860740       // bf16[128*128]
#define OFF_XS        868932       // bf16[50000*128] = X * norm_src (16B aligned)
// total = 4,068,932 words = 16.28 MB (< 16.47 MB proven in R4/R6)

typedef __attribute__((ext_vector_type(8))) __bf16 bf16x8;
typedef __attribute__((ext_vector_type(4))) float f32x4;

static __device__ __forceinline__ unsigned short f2bf(float f) {
    unsigned u = __float_as_uint(f);
    unsigned r = (u + 0x7FFFu + ((u >> 16) & 1u)) >> 16;
    return (unsigned short)r;
}
static __device__ __forceinline__ float bf2f(unsigned short h) {
    return __uint_as_float(((unsigned)h) << 16);
}

// ---------------- degrees (int2-vectorized) + fused W packing ----------------
// packW: frag (c=coltile 0..7, t=ktile 0..3): lane l holds B[t*32+(l>>4)*8+j][c*16+(l&15)]
__global__ void deg_pack_kernel(const int* __restrict__ src, const int* __restrict__ dst,
                                int* __restrict__ cnt_out, int* __restrict__ cnt_in,
                                const float* __restrict__ W, const float* __restrict__ Wres,
                                unsigned short* __restrict__ Wpk, unsigned short* __restrict__ Wrpk) {
    int i = blockIdx.x * 256 + threadIdx.x;
    if (i < 2048) {
        int l = i & 63;
        int t = (i >> 6) & 3;
        int c = i >> 8;
        int col = c * 16 + (l & 15);
        int k0 = t * 32 + (l >> 4) * 8;
        union { unsigned short us[8]; uint4 v; } u1, u2;
        #pragma unroll
        for (int j = 0; j < 8; ++j) {
            u1.us[j] = f2bf(W[(size_t)(k0 + j) * 128 + col]);
            u2.us[j] = f2bf(Wres[(size_t)(k0 + j) * 128 + col]);
        }
        ((uint4*)Wpk)[i] = u1.v;
        ((uint4*)Wrpk)[i] = u2.v;
    }
    if (i < N_EDGES / 2) {
        int2 s2 = ((const int2*)src)[i];
        int2 d2 = ((const int2*)dst)[i];
        atomicAdd(&cnt_out[s2.x], 1);
        atomicAdd(&cnt_out[s2.y], 1);
        atomicAdd(&cnt_in[d2.x], 1);
        atomicAdd(&cnt_in[d2.y], 1);
    }
}

// ---------------- X * rsqrt(deg_out) -> bf16 Xs ----------------
__global__ void cvt_kernel(const float* __restrict__ X, const int* __restrict__ cnt_out,
                           unsigned short* __restrict__ Xs) {
    int tid = blockIdx.x * 256 + threadIdx.x;
    if (tid >= N_NODES * 16) return;
    int row = tid >> 4;
    int sub = tid & 15;
    float wv = rsqrtf((float)max(cnt_out[row], 1));
    const float4* xp = (const float4*)(X + (size_t)row * 128 + sub * 8);
    float4 a = xp[0];
    float4 b = xp[1];
    union { unsigned short us[8]; uint4 u; } o;
    o.us[0] = f2bf(a.x * wv); o.us[1] = f2bf(a.y * wv);
    o.us[2] = f2bf(a.z * wv); o.us[3] = f2bf(a.w * wv);
    o.us[4] = f2bf(b.x * wv); o.us[5] = f2bf(b.y * wv);
    o.us[6] = f2bf(b.z * wv); o.us[7] = f2bf(b.w * wv);
    *(uint4*)(Xs + (size_t)row * 128 + sub * 8) = o.u;
}

// ---------------- scan level A: block sums of cnt_in ----------------
__global__ void scanA_kernel(const int* __restrict__ cnt_in, int* __restrict__ part) {
    __shared__ int wsum[4];
    int i = blockIdx.x * 256 + threadIdx.x;
    int v = (i < N_NODES) ? cnt_in[i] : 0;
    int lane = threadIdx.x & 63;
    int wid = threadIdx.x >> 6;
    int s = v;
    #pragma unroll
    for (int off = 32; off >= 1; off >>= 1) s += __shfl_xor(s, off);
    if (lane == 0) wsum[wid] = s;
    __syncthreads();
    if (threadIdx.x == 0) part[blockIdx.x] = wsum[0] + wsum[1] + wsum[2] + wsum[3];
}

// ---------------- scan C (fused B): prefix base via masked reduce + local scan; writes nd too ----------------
__global__ void scanC_kernel(const int* __restrict__ cnt_in, const int* __restrict__ part,
                             int* __restrict__ row_start, int* __restrict__ cursor,
                             float* __restrict__ nd) {
    __shared__ int wsumB[4];
    __shared__ int wsum[4];
    int t = threadIdx.x;
    int lane = t & 63;
    int wid = t >> 6;
    int pv = (t < NBLK_SCAN && t < (int)blockIdx.x) ? part[t] : 0;
    int sb = pv;
    #pragma unroll
    for (int off = 32; off >= 1; off >>= 1) sb += __shfl_xor(sb, off);
    if (lane == 0) wsumB[wid] = sb;
    int i = blockIdx.x * 256 + t;
    int v = (i < N_NODES) ? cnt_in[i] : 0;
    if (i < N_NODES) nd[i] = rsqrtf((float)max(v, 1));
    int s = v;
    #pragma unroll
    for (int off = 1; off < 64; off <<= 1) {
        int u = __shfl_up(s, off);
        if (lane >= off) s += u;
    }
    if (lane == 63) wsum[wid] = s;
    __syncthreads();
    int add = wsumB[0] + wsumB[1] + wsumB[2] + wsumB[3];
    for (int k = 0; k < wid; ++k) add += wsum[k];
    if (i < N_NODES) {
        int rs = add + s - v;
        row_start[i] = rs;
        cursor[i] = rs;
    }
    if (i == N_NODES) row_start[N_NODES] = N_EDGES;
}

// ---------------- CSR fill (int2-vectorized) ----------------
__global__ void fill_kernel(const int* __restrict__ src, const int* __restrict__ dst,
                            int* __restrict__ cursor, int* __restrict__ csr) {
    int i = blockIdx.x * blockDim.x + threadIdx.x;
    if (i < N_EDGES / 2) {
        int2 d2 = ((const int2*)dst)[i];
        int2 s2 = ((const int2*)src)[i];
        int p0 = atomicAdd(&cursor[d2.x], 1);
        csr[p0] = s2.x;
        int p1 = atomicAdd(&cursor[d2.y], 1);
        csr[p1] = s2.y;
    }
}

// ---------------- fused gather + dual MFMA GEMM + relu/residual + BN partials ----------------
// 1024 threads = 16 waves, block = one 16-row tile (grid 3125), ONE ROW PER WAVE.
// Gather: wave loads its row's csr segment once (coalesced, <=64 edges; rare fallback),
// then per 4-edge step the source index comes from __shfl (register, no mem dependency)
// -> all Xs loads pipeline. 16-lane group per edge, 16B per lane.
// MFMA: waves 0-7 each own coltile w (both GEMMs). Waves 8-15 gather only.
__global__ __launch_bounds__(1024) void fused_kernel(
    const float* __restrict__ X, const unsigned short* __restrict__ Xs,
    const int* __restrict__ csr, const int* __restrict__ row_start,
    const float* __restrict__ nd,
    const unsigned short* __restrict__ Wpk, const unsigned short* __restrict__ Wrpk,
    float* __restrict__ out, float* __restrict__ sums8, float* __restrict__ sumsq8) {
    __shared__ unsigned short P[16 * 136];  // 4.25KB, 272B row stride
    __shared__ float lsum[128];
    __shared__ float lsq[128];
    int t = threadIdx.x;
    int w = t >> 6;
    int l = t & 63;
    int sub = l & 15;   // col slice: cols sub*8 .. sub*8+7
    int grp = l >> 4;   // edge slot within a 4-edge step
    int rt = blockIdx.x;

    // ---- gather: this wave's row ----
    int node = rt * 16 + w;                 // wave-uniform
    int beg = row_start[node];
    int end = row_start[node + 1];
    float acc[8];
    #pragma unroll
    for (int j = 0; j < 8; ++j) acc[j] = 0.f;
    int n1 = min(end - beg, 64);
    int my_csr = (l < n1) ? csr[beg + l] : 0;
    for (int k = 0; k < n1; k += 4) {
        int s = __shfl(my_csr, k + grp);
        if (k + grp < n1) {
            uint4 v = *(const uint4*)(Xs + (size_t)s * 128 + sub * 8);
            acc[0] += __uint_as_float(v.x << 16);
            acc[1] += __uint_as_float(v.x & 0xFFFF0000u);
            acc[2] += __uint_as_float(v.y << 16);
            acc[3] += __uint_as_float(v.y & 0xFFFF0000u);
            acc[4] += __uint_as_float(v.z << 16);
            acc[5] += __uint_as_float(v.z & 0xFFFF0000u);
            acc[6] += __uint_as_float(v.w << 16);
            acc[7] += __uint_as_float(v.w & 0xFFFF0000u);
        }
    }
    // rare: degree > 64
    for (int e = beg + 64; e < end; e += 4) {
        if (e + grp < end) {
            int s = csr[e + grp];
            uint4 v = *(const uint4*)(Xs + (size_t)s * 128 + sub * 8);
            acc[0] += __uint_as_float(v.x << 16);
            acc[1] += __uint_as_float(v.x & 0xFFFF0000u);
            acc[2] += __uint_as_float(v.y << 16);
            acc[3] += __uint_as_float(v.y & 0xFFFF0000u);
            acc[4] += __uint_as_float(v.z << 16);
            acc[5] += __uint_as_float(v.z & 0xFFFF0000u);
            acc[6] += __uint_as_float(v.w << 16);
            acc[7] += __uint_as_float(v.w & 0xFFFF0000u);
        }
    }
    // combine 4 edge-groups, write row sum to LDS
    #pragma unroll
    for (int j = 0; j < 8; ++j) {
        acc[j] += __shfl_xor(acc[j], 16);
        acc[j] += __shfl_xor(acc[j], 32);
    }
    if (l < 16) {
        union { unsigned short us[8]; uint4 u; } o;
        #pragma unroll
        for (int j = 0; j < 8; ++j) o.us[j] = f2bf(acc[j]);
        *(uint4*)(&P[w * 136 + sub * 8]) = o.u;
    }
    __syncthreads();

    // ---- MFMA: waves 0-7, coltile c = w ----
    if (w < 8) {
        int kg = l >> 4;
        int lr = l & 15;
        int arow = rt * 16 + lr;           // always < 50000
        float ndv = nd[arow];
        bf16x8 a1[4], a2[4];
        #pragma unroll
        for (int kt = 0; kt < 4; ++kt) {
            union { unsigned short us[8]; uint4 v; bf16x8 b; } v0, o1, o2;
            v0.v = *(const uint4*)(&P[lr * 136 + kt * 32 + kg * 8]);
            #pragma unroll
            for (int j = 0; j < 8; ++j) o1.us[j] = f2bf(bf2f(v0.us[j]) * ndv);
            a1[kt] = o1.b;
            float4 xa = *(const float4*)(X + (size_t)arow * 128 + kt * 32 + kg * 8);
            float4 xb = *(const float4*)(X + (size_t)arow * 128 + kt * 32 + kg * 8 + 4);
            o2.us[0] = f2bf(xa.x); o2.us[1] = f2bf(xa.y); o2.us[2] = f2bf(xa.z); o2.us[3] = f2bf(xa.w);
            o2.us[4] = f2bf(xb.x); o2.us[5] = f2bf(xb.y); o2.us[6] = f2bf(xb.z); o2.us[7] = f2bf(xb.w);
            a2[kt] = o2.b;
        }
        const bf16x8* BW = (const bf16x8*)Wpk;
        const bf16x8* BR = (const bf16x8*)Wrpk;
        int c = w;
        f32x4 acc1 = {0.f, 0.f, 0.f, 0.f};
        f32x4 acc2 = {0.f, 0.f, 0.f, 0.f};
        #pragma unroll
        for (int kt = 0; kt < 4; ++kt)
            acc1 = __builtin_amdgcn_mfma_f32_16x16x32_bf16(a1[kt], BW[(c * 4 + kt) * 64 + l], acc1, 0, 0, 0);
        #pragma unroll
        for (int kt = 0; kt < 4; ++kt)
            acc2 = __builtin_amdgcn_mfma_f32_16x16x32_bf16(a2[kt], BR[(c * 4 + kt) * 64 + l], acc2, 0, 0, 0);
        int col = c * 16 + lr;
        float s = 0.f, s2 = 0.f;
        #pragma unroll
        for (int i = 0; i < 4; ++i) {
            int crow = rt * 16 + kg * 4 + i;  // C/D: col=lane&15, row=(lane>>4)*4+i
            float v = fmaxf(acc1[i], 0.f) + fmaxf(acc2[i], 0.f);
            out[(size_t)crow * 128 + col] = v;
            s += v;
            s2 += v * v;
        }
        s += __shfl_xor(s, 16);
        s2 += __shfl_xor(s2, 16);
        s += __shfl_xor(s, 32);
        s2 += __shfl_xor(s2, 32);
        if (l < 16) {
            lsum[col] = s;   // each col written by exactly one wave/lane
            lsq[col] = s2;
        }
    }
    __syncthreads();
    if (t < 128) {
        int slot = (blockIdx.x & 7) * 128 + t;
        atomicAdd(&sums8[slot], lsum[t]);
        atomicAdd(&sumsq8[slot], lsq[t]);
    }
}

// ---------------- BatchNorm apply (8-slot reduce in LDS, in-place float4) ----------------
__global__ void bn_apply_kernel(float* __restrict__ out, const float* __restrict__ sums8,
                                const float* __restrict__ sumsq8, const float* __restrict__ gamma,
                                const float* __restrict__ beta) {
    __shared__ float lmean[128], linv[128], lg[128], lb[128];
    int t = threadIdx.x;
    if (t < 128) {
        float s = 0.f, s2 = 0.f;
        #pragma unroll
        for (int k = 0; k < 8; ++k) {
            s += sums8[k * 128 + t];
            s2 += sumsq8[k * 128 + t];
        }
        const float invN = 1.0f / (float)N_NODES;
        float m = s * invN;
        lmean[t] = m;
        linv[t] = rsqrtf(s2 * invN - m * m + BN_EPS);
        lg[t] = gamma[t];
        lb[t] = beta[t];
    }
    __syncthreads();
    int tid = blockIdx.x * 256 + t;
    if (tid >= N_NODES * D / 4) return;
    int d0 = (tid * 4) & 127;
    float4 v = ((float4*)out)[tid];
    v.x = lg[d0] * (v.x - lmean[d0]) * linv[d0] + lb[d0];
    v.y = lg[d0 + 1] * (v.y - lmean[d0 + 1]) * linv[d0 + 1] + lb[d0 + 1];
    v.z = lg[d0 + 2] * (v.z - lmean[d0 + 2]) * linv[d0 + 2] + lb[d0 + 2];
    v.w = lg[d0 + 3] * (v.w - lmean[d0 + 3]) * linv[d0 + 3] + lb[d0 + 3];
    ((float4*)out)[tid] = v;
}

extern "C" void kernel_launch(void* const* d_in, const int* in_sizes, int n_in,
                              void* d_out, int out_size, void* d_ws, size_t ws_size,
                              hipStream_t stream) {
    const float* X = (const float*)d_in[0];
    const float* W = (const float*)d_in[1];
    const float* Wres = (const float*)d_in[2];
    const float* gamma = (const float*)d_in[3];
    const float* beta = (const float*)d_in[4];
    const int* src = (const int*)d_in[5];
    const int* dst = (const int*)d_in[6];
    float* out = (float*)d_out;

    int* wsI = (int*)d_ws;
    int* cnt_out = wsI + OFF_CNT_OUT;
    int* cnt_in = wsI + OFF_CNT_IN;
    float* sums8 = (float*)(wsI + OFF_SUMS8);
    float* sumsq8 = (float*)(wsI + OFF_SUMSQ8);
    int* part = wsI + OFF_PART;
    float* nd = (float*)(wsI + OFF_ND);
    int* row_start = wsI + OFF_ROWSTART;
    int* cursor = wsI + OFF_CURSOR;
    int* csr = wsI + OFF_CSR;
    unsigned short* Wpk = (unsigned short*)(wsI + OFF_WPK);
    unsigned short* Wrpk = (unsigned short*)(wsI + OFF_WRPK);
    unsigned short* Xs = (unsigned short*)(wsI + OFF_XS);

    hipMemsetAsync(d_ws, 0, (size_t)ZERO_WORDS * 4, stream);

    deg_pack_kernel<<<(N_EDGES / 2 + 255) / 256, 256, 0, stream>>>(src, dst, cnt_out, cnt_in,
                                                                   W, Wres, Wpk, Wrpk);
    cvt_kernel<<<(N_NODES * 16 + 255) / 256, 256, 0, stream>>>(X, cnt_out, Xs);
    scanA_kernel<<<NBLK_SCAN, 256, 0, stream>>>(cnt_in, part);
    scanC_kernel<<<NBLK_SCAN, 256, 0, stream>>>(cnt_in, part, row_start, cursor, nd);
    fill_kernel<<<(N_EDGES / 2 + 255) / 256, 256, 0, stream>>>(src, dst, cursor, csr);
    fused_kernel<<<N_NODES / 16, 1024, 0, stream>>>(X, Xs, csr, row_start, nd,
                                                    Wpk, Wrpk, out, sums8, sumsq8);
    bn_apply_kernel<<<(N_NODES * D / 4 + 255) / 256, 256, 0, stream>>>(out, sums8, sumsq8,
                                                                       gamma, beta);
}

// Round 11
// 166.018 us; speedup vs baseline: 1.1016x; 1.0507x over previous
//
#include <hip/hip_runtime.h>

#define N_NODES 50000
#define N_EDGES 600000
#define D 128
#define BN_EPS 1e-5f
#define NBLK_SCAN 196   // ceil(50000/256)

// ws layout in 4-byte words:
#define OFF_CNT_OUT   0            // int[50048]
#define OFF_CNT_IN    50048        // int[50048]
#define OFF_SUMS8     100096       // float[8*128]
#define OFF_SUMSQ8    101120       // float[8*128]
#define ZERO_WORDS    102144       // memset range each call
#define OFF_PART      102144       // int[256] (fully overwritten)
#define OFF_ND        102400       // float[50048]
#define OFF_ROWSTART  152448       // int[50052]
#define OFF_CURSOR    202500       // int[50048]
#define OFF_CSR       252548       // int[600000]
#define OFF_WPK       852548       // bf16[128*128] packed B-frags (16B aligned)
#define OFF_WRPK      860740       // bf16[128*128]
#define OFF_XS        868932       // bf16[50000*128] = X * norm_src (16B aligned)
// total = 4,068,932 words = 16.28 MB (< 16.47 MB proven in R4/R6)

typedef __attribute__((ext_vector_type(8))) __bf16 bf16x8;
typedef __attribute__((ext_vector_type(4))) float f32x4;

static __device__ __forceinline__ unsigned short f2bf(float f) {
    unsigned u = __float_as_uint(f);
    unsigned r = (u + 0x7FFFu + ((u >> 16) & 1u)) >> 16;
    return (unsigned short)r;
}
static __device__ __forceinline__ float bf2f(unsigned short h) {
    return __uint_as_float(((unsigned)h) << 16);
}

// ---------------- degrees (int2-vectorized) + fused W packing ----------------
// packW: frag (c=coltile 0..7, t=ktile 0..3): lane l holds B[t*32+(l>>4)*8+j][c*16+(l&15)]
__global__ void deg_pack_kernel(const int* __restrict__ src, const int* __restrict__ dst,
                                int* __restrict__ cnt_out, int* __restrict__ cnt_in,
                                const float* __restrict__ W, const float* __restrict__ Wres,
                                unsigned short* __restrict__ Wpk, unsigned short* __restrict__ Wrpk) {
    int i = blockIdx.x * 256 + threadIdx.x;
    if (i < 2048) {
        int l = i & 63;
        int t = (i >> 6) & 3;
        int c = i >> 8;
        int col = c * 16 + (l & 15);
        int k0 = t * 32 + (l >> 4) * 8;
        union { unsigned short us[8]; uint4 v; } u1, u2;
        #pragma unroll
        for (int j = 0; j < 8; ++j) {
            u1.us[j] = f2bf(W[(size_t)(k0 + j) * 128 + col]);
            u2.us[j] = f2bf(Wres[(size_t)(k0 + j) * 128 + col]);
        }
        ((uint4*)Wpk)[i] = u1.v;
        ((uint4*)Wrpk)[i] = u2.v;
    }
    if (i < N_EDGES / 2) {
        int2 s2 = ((const int2*)src)[i];
        int2 d2 = ((const int2*)dst)[i];
        atomicAdd(&cnt_out[s2.x], 1);
        atomicAdd(&cnt_out[s2.y], 1);
        atomicAdd(&cnt_in[d2.x], 1);
        atomicAdd(&cnt_in[d2.y], 1);
    }
}

// ---------------- X * rsqrt(deg_out) -> bf16 Xs, + scanA (blocks < 196) ----------------
__global__ void cvt_scanA_kernel(const float* __restrict__ X, const int* __restrict__ cnt_out,
                                 const int* __restrict__ cnt_in, unsigned short* __restrict__ Xs,
                                 int* __restrict__ part) {
    if (blockIdx.x < NBLK_SCAN) {
        __shared__ int wsum[4];
        int i = blockIdx.x * 256 + threadIdx.x;
        int v = (i < N_NODES) ? cnt_in[i] : 0;
        int lane = threadIdx.x & 63;
        int wid = threadIdx.x >> 6;
        #pragma unroll
        for (int off = 32; off >= 1; off >>= 1) v += __shfl_xor(v, off);
        if (lane == 0) wsum[wid] = v;
        __syncthreads();
        if (threadIdx.x == 0) part[blockIdx.x] = wsum[0] + wsum[1] + wsum[2] + wsum[3];
    }
    int tid = blockIdx.x * 256 + threadIdx.x;
    if (tid >= N_NODES * 16) return;
    int row = tid >> 4;
    int sub = tid & 15;
    float wv = rsqrtf((float)max(cnt_out[row], 1));
    const float4* xp = (const float4*)(X + (size_t)row * 128 + sub * 8);
    float4 a = xp[0];
    float4 b = xp[1];
    union { unsigned short us[8]; uint4 u; } o;
    o.us[0] = f2bf(a.x * wv); o.us[1] = f2bf(a.y * wv);
    o.us[2] = f2bf(a.z * wv); o.us[3] = f2bf(a.w * wv);
    o.us[4] = f2bf(b.x * wv); o.us[5] = f2bf(b.y * wv);
    o.us[6] = f2bf(b.z * wv); o.us[7] = f2bf(b.w * wv);
    *(uint4*)(Xs + (size_t)row * 128 + sub * 8) = o.u;
}

// ---------------- scan C (fused B): prefix base via masked reduce + local scan; writes nd too ----------------
__global__ void scanC_kernel(const int* __restrict__ cnt_in, const int* __restrict__ part,
                             int* __restrict__ row_start, int* __restrict__ cursor,
                             float* __restrict__ nd) {
    __shared__ int wsumB[4];
    __shared__ int wsum[4];
    int t = threadIdx.x;
    int lane = t & 63;
    int wid = t >> 6;
    int pv = (t < NBLK_SCAN && t < (int)blockIdx.x) ? part[t] : 0;
    int sb = pv;
    #pragma unroll
    for (int off = 32; off >= 1; off >>= 1) sb += __shfl_xor(sb, off);
    if (lane == 0) wsumB[wid] = sb;
    int i = blockIdx.x * 256 + t;
    int v = (i < N_NODES) ? cnt_in[i] : 0;
    if (i < N_NODES) nd[i] = rsqrtf((float)max(v, 1));
    int s = v;
    #pragma unroll
    for (int off = 1; off < 64; off <<= 1) {
        int u = __shfl_up(s, off);
        if (lane >= off) s += u;
    }
    if (lane == 63) wsum[wid] = s;
    __syncthreads();
    int add = wsumB[0] + wsumB[1] + wsumB[2] + wsumB[3];
    for (int k = 0; k < wid; ++k) add += wsum[k];
    if (i < N_NODES) {
        int rs = add + s - v;
        row_start[i] = rs;
        cursor[i] = rs;
    }
    if (i == N_NODES) row_start[N_NODES] = N_EDGES;
}

// ---------------- CSR fill (int2-vectorized) ----------------
__global__ void fill_kernel(const int* __restrict__ src, const int* __restrict__ dst,
                            int* __restrict__ cursor, int* __restrict__ csr) {
    int i = blockIdx.x * blockDim.x + threadIdx.x;
    if (i < N_EDGES / 2) {
        int2 d2 = ((const int2*)dst)[i];
        int2 s2 = ((const int2*)src)[i];
        int p0 = atomicAdd(&cursor[d2.x], 1);
        csr[p0] = s2.x;
        int p1 = atomicAdd(&cursor[d2.y], 1);
        csr[p1] = s2.y;
    }
}

// ---------------- fused gather + dual MFMA GEMM + relu/residual + BN partials ----------------
// 256 threads = 4 waves, block = one 16-row tile (grid 3125).
// Gather: LANE-PARALLEL ROWS — 16-lane group g of wave w owns row w*4+g alone.
// Each group iterates its own edge list (exec-masked divergence across groups),
// 4-edge unroll -> 4 csr + 4 Xs loads in flight per group, 4 groups independent.
// No cross-group combine: group writes its full 128-col row sum straight to LDS.
// MFMA: wave w does coltiles 2w, 2w+1.
__global__ __launch_bounds__(256) void fused_kernel(
    const float* __restrict__ X, const unsigned short* __restrict__ Xs,
    const int* __restrict__ csr, const int* __restrict__ row_start,
    const float* __restrict__ nd,
    const unsigned short* __restrict__ Wpk, const unsigned short* __restrict__ Wrpk,
    float* __restrict__ out, float* __restrict__ sums8, float* __restrict__ sumsq8) {
    __shared__ unsigned short P[16 * 136];  // 4.25KB, 272B row stride
    __shared__ float lsum[128];
    __shared__ float lsq[128];
    int t = threadIdx.x;
    int w = t >> 6;
    int l = t & 63;
    int sub = l & 15;   // col slice: cols sub*8 .. sub*8+7
    int g = l >> 4;     // group id = row within wave's quad
    int rt = blockIdx.x;

    // ---- gather: group-owned row ----
    int node = rt * 16 + w * 4 + g;
    int beg = row_start[node];       // broadcast within group
    int end = row_start[node + 1];
    float acc[8];
    #pragma unroll
    for (int j = 0; j < 8; ++j) acc[j] = 0.f;
    int e = beg;
    for (; e + 3 < end; e += 4) {
        int s0 = csr[e], s1 = csr[e + 1], s2 = csr[e + 2], s3 = csr[e + 3];
        uint4 v0 = *(const uint4*)(Xs + (size_t)s0 * 128 + sub * 8);
        uint4 v1 = *(const uint4*)(Xs + (size_t)s1 * 128 + sub * 8);
        uint4 v2 = *(const uint4*)(Xs + (size_t)s2 * 128 + sub * 8);
        uint4 v3 = *(const uint4*)(Xs + (size_t)s3 * 128 + sub * 8);
        acc[0] += __uint_as_float(v0.x << 16) + __uint_as_float(v1.x << 16) +
                  __uint_as_float(v2.x << 16) + __uint_as_float(v3.x << 16);
        acc[1] += __uint_as_float(v0.x & 0xFFFF0000u) + __uint_as_float(v1.x & 0xFFFF0000u) +
                  __uint_as_float(v2.x & 0xFFFF0000u) + __uint_as_float(v3.x & 0xFFFF0000u);
        acc[2] += __uint_as_float(v0.y << 16) + __uint_as_float(v1.y << 16) +
                  __uint_as_float(v2.y << 16) + __uint_as_float(v3.y << 16);
        acc[3] += __uint_as_float(v0.y & 0xFFFF0000u) + __uint_as_float(v1.y & 0xFFFF0000u) +
                  __uint_as_float(v2.y & 0xFFFF0000u) + __uint_as_float(v3.y & 0xFFFF0000u);
        acc[4] += __uint_as_float(v0.z << 16) + __uint_as_float(v1.z << 16) +
                  __uint_as_float(v2.z << 16) + __uint_as_float(v3.z << 16);
        acc[5] += __uint_as_float(v0.z & 0xFFFF0000u) + __uint_as_float(v1.z & 0xFFFF0000u) +
                  __uint_as_float(v2.z & 0xFFFF0000u) + __uint_as_float(v3.z & 0xFFFF0000u);
        acc[6] += __uint_as_float(v0.w << 16) + __uint_as_float(v1.w << 16) +
                  __uint_as_float(v2.w << 16) + __uint_as_float(v3.w << 16);
        acc[7] += __uint_as_float(v0.w & 0xFFFF0000u) + __uint_as_float(v1.w & 0xFFFF0000u) +
                  __uint_as_float(v2.w & 0xFFFF0000u) + __uint_as_float(v3.w & 0xFFFF0000u);
    }
    for (; e < end; ++e) {
        int s0 = csr[e];
        uint4 v0 = *(const uint4*)(Xs + (size_t)s0 * 128 + sub * 8);
        acc[0] += __uint_as_float(v0.x << 16);
        acc[1] += __uint_as_float(v0.x & 0xFFFF0000u);
        acc[2] += __uint_as_float(v0.y << 16);
        acc[3] += __uint_as_float(v0.y & 0xFFFF0000u);
        acc[4] += __uint_as_float(v0.z << 16);
        acc[5] += __uint_as_float(v0.z & 0xFFFF0000u);
        acc[6] += __uint_as_float(v0.w << 16);
        acc[7] += __uint_as_float(v0.w & 0xFFFF0000u);
    }
    // group writes its full row sum (no combine needed)
    {
        union { unsigned short us[8]; uint4 u; } o;
        #pragma unroll
        for (int j = 0; j < 8; ++j) o.us[j] = f2bf(acc[j]);
        *(uint4*)(&P[(w * 4 + g) * 136 + sub * 8]) = o.u;
    }
    __syncthreads();

    // ---- fragment loads: A1 from P (* nd), A2 from f32 X ----
    int kg = l >> 4;
    int lr = l & 15;
    int arow = rt * 16 + lr;           // always < 50000
    float ndv = nd[arow];
    bf16x8 a1[4], a2[4];
    #pragma unroll
    for (int kt = 0; kt < 4; ++kt) {
        union { unsigned short us[8]; uint4 v; bf16x8 b; } v0, o1, o2;
        v0.v = *(const uint4*)(&P[lr * 136 + kt * 32 + kg * 8]);
        #pragma unroll
        for (int j = 0; j < 8; ++j) o1.us[j] = f2bf(bf2f(v0.us[j]) * ndv);
        a1[kt] = o1.b;
        float4 xa = *(const float4*)(X + (size_t)arow * 128 + kt * 32 + kg * 8);
        float4 xb = *(const float4*)(X + (size_t)arow * 128 + kt * 32 + kg * 8 + 4);
        o2.us[0] = f2bf(xa.x); o2.us[1] = f2bf(xa.y); o2.us[2] = f2bf(xa.z); o2.us[3] = f2bf(xa.w);
        o2.us[4] = f2bf(xb.x); o2.us[5] = f2bf(xb.y); o2.us[6] = f2bf(xb.z); o2.us[7] = f2bf(xb.w);
        a2[kt] = o2.b;
    }
    const bf16x8* BW = (const bf16x8*)Wpk;
    const bf16x8* BR = (const bf16x8*)Wrpk;

    // ---- MFMA + epilogue: wave w handles coltiles 2w, 2w+1 (col partition -> plain stores) ----
    #pragma unroll
    for (int ci = 0; ci < 2; ++ci) {
        int c = w * 2 + ci;
        f32x4 acc1 = {0.f, 0.f, 0.f, 0.f};
        f32x4 acc2 = {0.f, 0.f, 0.f, 0.f};
        #pragma unroll
        for (int kt = 0; kt < 4; ++kt)
            acc1 = __builtin_amdgcn_mfma_f32_16x16x32_bf16(a1[kt], BW[(c * 4 + kt) * 64 + l], acc1, 0, 0, 0);
        #pragma unroll
        for (int kt = 0; kt < 4; ++kt)
            acc2 = __builtin_amdgcn_mfma_f32_16x16x32_bf16(a2[kt], BR[(c * 4 + kt) * 64 + l], acc2, 0, 0, 0);
        int col = c * 16 + lr;
        float s = 0.f, s2 = 0.f;
        #pragma unroll
        for (int i = 0; i < 4; ++i) {
            int crow = rt * 16 + kg * 4 + i;  // C/D: col=lane&15, row=(lane>>4)*4+i
            float v = fmaxf(acc1[i], 0.f) + fmaxf(acc2[i], 0.f);
            out[(size_t)crow * 128 + col] = v;
            s += v;
            s2 += v * v;
        }
        s += __shfl_xor(s, 16);
        s2 += __shfl_xor(s2, 16);
        s += __shfl_xor(s, 32);
        s2 += __shfl_xor(s2, 32);
        if (l < 16) {
            lsum[col] = s;   // each col written by exactly one wave/lane
            lsq[col] = s2;
        }
    }
    __syncthreads();
    if (t < 128) {
        int slot = (blockIdx.x & 7) * 128 + t;
        atomicAdd(&sums8[slot], lsum[t]);
        atomicAdd(&sumsq8[slot], lsq[t]);
    }
}

// ---------------- BatchNorm apply (8-slot reduce in LDS, in-place float4) ----------------
__global__ void bn_apply_kernel(float* __restrict__ out, const float* __restrict__ sums8,
                                const float* __restrict__ sumsq8, const float* __restrict__ gamma,
                                const float* __restrict__ beta) {
    __shared__ float lmean[128], linv[128], lg[128], lb[128];
    int t = threadIdx.x;
    if (t < 128) {
        float s = 0.f, s2 = 0.f;
        #pragma unroll
        for (int k = 0; k < 8; ++k) {
            s += sums8[k * 128 + t];
            s2 += sumsq8[k * 128 + t];
        }
        const float invN = 1.0f / (float)N_NODES;
        float m = s * invN;
        lmean[t] = m;
        linv[t] = rsqrtf(s2 * invN - m * m + BN_EPS);
        lg[t] = gamma[t];
        lb[t] = beta[t];
    }
    __syncthreads();
    int tid = blockIdx.x * 256 + t;
    if (tid >= N_NODES * D / 4) return;
    int d0 = (tid * 4) & 127;
    float4 v = ((float4*)out)[tid];
    v.x = lg[d0] * (v.x - lmean[d0]) * linv[d0] + lb[d0];
    v.y = lg[d0 + 1] * (v.y - lmean[d0 + 1]) * linv[d0 + 1] + lb[d0 + 1];
    v.z = lg[d0 + 2] * (v.z - lmean[d0 + 2]) * linv[d0 + 2] + lb[d0 + 2];
    v.w = lg[d0 + 3] * (v.w - lmean[d0 + 3]) * linv[d0 + 3] + lb[d0 + 3];
    ((float4*)out)[tid] = v;
}

extern "C" void kernel_launch(void* const* d_in, const int* in_sizes, int n_in,
                              void* d_out, int out_size, void* d_ws, size_t ws_size,
                              hipStream_t stream) {
    const float* X = (const float*)d_in[0];
    const float* W = (const float*)d_in[1];
    const float* Wres = (const float*)d_in[2];
    const float* gamma = (const float*)d_in[3];
    const float* beta = (const float*)d_in[4];
    const int* src = (const int*)d_in[5];
    const int* dst = (const int*)d_in[6];
    float* out = (float*)d_out;

    int* wsI = (int*)d_ws;
    int* cnt_out = wsI + OFF_CNT_OUT;
    int* cnt_in = wsI + OFF_CNT_IN;
    float* sums8 = (float*)(wsI + OFF_SUMS8);
    float* sumsq8 = (float*)(wsI + OFF_SUMSQ8);
    int* part = wsI + OFF_PART;
    float* nd = (float*)(wsI + OFF_ND);
    int* row_start = wsI + OFF_ROWSTART;
    int* cursor = wsI + OFF_CURSOR;
    int* csr = wsI + OFF_CSR;
    unsigned short* Wpk = (unsigned short*)(wsI + OFF_WPK);
    unsigned short* Wrpk = (unsigned short*)(wsI + OFF_WRPK);
    unsigned short* Xs = (unsigned short*)(wsI + OFF_XS);

    hipMemsetAsync(d_ws, 0, (size_t)ZERO_WORDS * 4, stream);

    deg_pack_kernel<<<(N_EDGES / 2 + 255) / 256, 256, 0, stream>>>(src, dst, cnt_out, cnt_in,
                                                                   W, Wres, Wpk, Wrpk);
    cvt_scanA_kernel<<<(N_NODES * 16 + 255) / 256, 256, 0, stream>>>(X, cnt_out, cnt_in, Xs, part);
    scanC_kernel<<<NBLK_SCAN, 256, 0, stream>>>(cnt_in, part, row_start, cursor, nd);
    fill_kernel<<<(N_EDGES / 2 + 255) / 256, 256, 0, stream>>>(src, dst, cursor, csr);
    fused_kernel<<<N_NODES / 16, 256, 0, stream>>>(X, Xs, csr, row_start, nd,
                                                   Wpk, Wrpk, out, sums8, sumsq8);
    bn_apply_kernel<<<(N_NODES * D / 4 + 255) / 256, 256, 0, stream>>>(out, sums8, sumsq8,
                                                                       gamma, beta);
}